// Round 5
// baseline (261.412 us; speedup 1.0000x reference)
//
#include <hip/hip_runtime.h>
#include <math.h>

#define BATCH 16
#define HW 262144          // 512*512
#define KSEL 26214         // int(0.1 * 262144)
#define MCAND 80           // TOP_K * CAND_MULT
#define TOPK 5
#define CAP 2048

// ---------------------------------------------------------------------------
// In-place radix-2 FFT, N=512, on LDS float re[]/im[]:
//   forward DIF: natural input -> bit-reversed output
//   inverse DIT: bit-reversed input -> natural output
// DIT(DIF(x)) = N*x elementwise, so the bit-reversed intermediate order is
// unobservable (phase normalize is elementwise; axes are independent).
// Twiddles via HW v_sin/v_cos (argument in revolutions, |rev| <= 0.5).
// Verified pairing by hand at N=4.
// ---------------------------------------------------------------------------

// Gaussian blur coefficients, sigma=1, 5-tap.
#define GW0 0.05448868454964294f
#define GW1 0.24420134200323332f
#define GW2 0.40261994689424746f

// K1: window + forward DIF FFT along W. One block per (b, h) row.
// Output A row-major, W index in bit-reversed storage order.
__global__ void k_win_rowfft(const float* __restrict__ img, float2* __restrict__ A) {
    __shared__ float re[512], im[512];
    int row = blockIdx.x;           // b*512 + h
    int h = row & 511;
    int t = threadIdx.x;
    float wr = 0.5f * (1.0f - __builtin_amdgcn_cosf((float)h * (1.0f / 511.0f)));
    const float* p = img + (size_t)row * 512;
    for (int i = t; i < 512; i += 256) {
        float wc = 0.5f * (1.0f - __builtin_amdgcn_cosf((float)i * (1.0f / 511.0f)));
        re[i] = p[i] * wr * wc;
        im[i] = 0.0f;
    }
    __syncthreads();
    #pragma unroll
    for (int hh = 256; hh >= 1; hh >>= 1) {
        int r = t & (hh - 1);
        int j = ((t & ~(hh - 1)) << 1) | r;
        float rev = -((float)r * (0.5f / (float)hh));
        float sn = __builtin_amdgcn_sinf(rev);
        float cs = __builtin_amdgcn_cosf(rev);
        float ax = re[j], ay = im[j];
        float bx = re[j + hh], by = im[j + hh];
        re[j] = ax + bx; im[j] = ay + by;
        float cx = ax - bx, cy = ay - by;
        re[j + hh] = cs * cx - sn * cy;
        im[j + hh] = cs * cy + sn * cx;
        __syncthreads();
    }
    float2* out = A + (size_t)row * 512;
    for (int i = t; i < 512; i += 256) out[i] = make_float2(re[i], im[i]);
}

// Fused H-axis pass, directly on columns (no transpose):
// load 512x8 column tile -> fwd DIF along H -> phase-only normalize ->
// inv DIT along H -> store back. 1024 blocks = 16 images x 64 col-groups.
#define CSTR 516   // LDS column stride (floats); 516%32=4 -> banks (4c+e)%32, conflict-free across c
__global__ void k_colfft(float2* __restrict__ X) {
    __shared__ float re[8 * CSTR];
    __shared__ float im[8 * CSTR];
    int b = blockIdx.x >> 6;
    int c0 = (blockIdx.x & 63) * 8;
    int t = threadIdx.x;
    float2* base = X + ((size_t)b * 512) * 512 + c0;
    #pragma unroll
    for (int ii = 0; ii < 16; ++ii) {
        int linear = ii * 256 + t;
        int c = linear & 7, e = linear >> 3;
        float2 v = base[(size_t)e * 512 + c];
        re[c * CSTR + e] = v.x;
        im[c * CSTR + e] = v.y;
    }
    __syncthreads();
    int c = t & 7, tt = t >> 3;
    float* cr = re + c * CSTR;
    float* ci = im + c * CSTR;
    // forward DIF along H
    #pragma unroll
    for (int hh = 256; hh >= 1; hh >>= 1) {
        #pragma unroll
        for (int kk = 0; kk < 8; ++kk) {
            int k = kk * 32 + tt;
            int r = k & (hh - 1);
            int j = ((k & ~(hh - 1)) << 1) | r;
            float rev = -((float)r * (0.5f / (float)hh));
            float sn = __builtin_amdgcn_sinf(rev);
            float cs = __builtin_amdgcn_cosf(rev);
            float ax = cr[j], ay = ci[j];
            float bx = cr[j + hh], by = ci[j + hh];
            cr[j] = ax + bx; ci[j] = ay + by;
            float cx = ax - bx, cy = ay - by;
            cr[j + hh] = cs * cx - sn * cy;
            ci[j + hh] = cs * cy + sn * cx;
        }
        __syncthreads();
    }
    // phase-only normalize (elementwise; order-agnostic)
    #pragma unroll
    for (int ii = 0; ii < 16; ++ii) {
        int linear = ii * 256 + t;
        int cc = linear & 7, e = linear >> 3;
        int a = cc * CSTR + e;
        float x = re[a], y = im[a];
        float m2 = x * x + y * y;
        if (m2 > 0.0f) {
            float inv = rsqrtf(m2);
            re[a] = x * inv; im[a] = y * inv;
        } else {
            re[a] = 1.0f; im[a] = 0.0f;
        }
    }
    __syncthreads();
    // inverse DIT along H
    #pragma unroll
    for (int hh = 1; hh <= 256; hh <<= 1) {
        #pragma unroll
        for (int kk = 0; kk < 8; ++kk) {
            int k = kk * 32 + tt;
            int r = k & (hh - 1);
            int j = ((k & ~(hh - 1)) << 1) | r;
            float rev = (float)r * (0.5f / (float)hh);
            float sn = __builtin_amdgcn_sinf(rev);
            float cs = __builtin_amdgcn_cosf(rev);
            float ax = cr[j], ay = ci[j];
            float bx0 = cr[j + hh], by0 = ci[j + hh];
            float bx = cs * bx0 - sn * by0;
            float by = cs * by0 + sn * bx0;
            cr[j] = ax + bx; ci[j] = ay + by;
            cr[j + hh] = ax - bx; ci[j + hh] = ay - by;
        }
        __syncthreads();
    }
    #pragma unroll
    for (int ii = 0; ii < 16; ++ii) {
        int linear = ii * 256 + t;
        int cc = linear & 7, e = linear >> 3;
        base[(size_t)e * 512 + cc] = make_float2(re[cc * CSTR + e], im[cc * CSTR + e]);
    }
}

// Final inverse DIT FFT along W (bit-rev input) + 1/(H*W) scaling + |.|^2
// + horizontal 5-tap blur.
__global__ void k_mag_hblur(const float2* __restrict__ X, float* __restrict__ out) {
    __shared__ float re[512], im[512], smag[512];
    int row = blockIdx.x;
    int t = threadIdx.x;
    const float2* p = X + (size_t)row * 512;
    for (int i = t; i < 512; i += 256) {
        float2 v = p[i];
        re[i] = v.x; im[i] = v.y;
    }
    __syncthreads();
    #pragma unroll
    for (int hh = 1; hh <= 256; hh <<= 1) {
        int r = t & (hh - 1);
        int j = ((t & ~(hh - 1)) << 1) | r;
        float rev = (float)r * (0.5f / (float)hh);
        float sn = __builtin_amdgcn_sinf(rev);
        float cs = __builtin_amdgcn_cosf(rev);
        float ax = re[j], ay = im[j];
        float bx0 = re[j + hh], by0 = im[j + hh];
        float bx = cs * bx0 - sn * by0;
        float by = cs * by0 + sn * bx0;
        re[j] = ax + bx; im[j] = ay + by;
        re[j + hh] = ax - bx; im[j + hh] = ay - by;
        __syncthreads();
    }
    const float s = 3.814697265625e-06f;   // 1/262144, exact
    for (int i = t; i < 512; i += 256) {
        float rr = re[i] * s, ii = im[i] * s;
        smag[i] = rr * rr + ii * ii;
    }
    __syncthreads();
    float* o = out + (size_t)row * 512;
    for (int i = t; i < 512; i += 256) {
        float acc = GW2 * smag[i];
        if (i >= 1)   acc += GW1 * smag[i - 1];
        if (i >= 2)   acc += GW0 * smag[i - 2];
        if (i <= 510) acc += GW1 * smag[i + 1];
        if (i <= 509) acc += GW0 * smag[i + 2];
        o[i] = acc;
    }
}

// Vertical blur + per-BLOCK min/max partials (no atomics).
__global__ void k_vblur(const float* __restrict__ in, float* __restrict__ out,
                        float* __restrict__ pmn, float* __restrict__ pmx) {
    __shared__ float smn[256];
    __shared__ float smx[256];
    int t = threadIdx.x;
    int i = blockIdx.x * 256 + t;
    int y = (i >> 9) & 511;
    float acc = GW2 * in[i];
    if (y >= 1)   acc += GW1 * in[i - 512];
    if (y >= 2)   acc += GW0 * in[i - 1024];
    if (y <= 510) acc += GW1 * in[i + 512];
    if (y <= 509) acc += GW0 * in[i + 1024];
    out[i] = acc;
    smn[t] = acc; smx[t] = acc;
    __syncthreads();
    for (int s = 128; s > 0; s >>= 1) {
        if (t < s) { smn[t] = fminf(smn[t], smn[t + s]); smx[t] = fmaxf(smx[t], smx[t + s]); }
        __syncthreads();
    }
    if (t == 0) { pmn[blockIdx.x] = smn[0]; pmx[blockIdx.x] = smx[0]; }
}

// Fold 1024 partials per image -> mnf/mxf.
__global__ void k_reduce(const float* __restrict__ pmn, const float* __restrict__ pmx,
                         float* __restrict__ mnf, float* __restrict__ mxf) {
    __shared__ float smn[256];
    __shared__ float smx[256];
    int b = blockIdx.x, t = threadIdx.x;
    float lmn = INFINITY, lmx = -INFINITY;
    for (int j = t; j < 1024; j += 256) {
        lmn = fminf(lmn, pmn[b * 1024 + j]);
        lmx = fmaxf(lmx, pmx[b * 1024 + j]);
    }
    smn[t] = lmn; smx[t] = lmx;
    __syncthreads();
    for (int s = 128; s > 0; s >>= 1) {
        if (t < s) { smn[t] = fminf(smn[t], smn[t + s]); smx[t] = fmaxf(smx[t], smx[t + s]); }
        __syncthreads();
    }
    if (t == 0) { mnf[b] = smn[0]; mxf[b] = smx[0]; }
}

// Normalize + border mask -> final saliency (d_out), fused with hist round 1.
__global__ void k_norm_hist(const float* __restrict__ in, const float* __restrict__ mnf,
                            const float* __restrict__ mxf, float* __restrict__ out,
                            unsigned int* __restrict__ g) {
    __shared__ unsigned int h[4096];
    int t = threadIdx.x;
    int b = blockIdx.x >> 5;
    int base = b * HW + (blockIdx.x & 31) * 8192;
    float mn = mnf[b], mx = mxf[b];
    float inv = 1.0f / (mx - mn + 1e-8f);
    for (int i = t; i < 4096; i += 256) h[i] = 0u;
    __syncthreads();
    for (int j = 0; j < 32; ++j) {
        int idx = base + j * 256 + t;
        float v = (in[idx] - mn) * inv;
        int xx = idx & 511, yy = (idx >> 9) & 511;
        bool inside = (xx >= 12) && (xx < 500) && (yy >= 12) && (yy < 500);
        v = inside ? v : 0.0f;
        out[idx] = v;
        atomicAdd(&h[__float_as_uint(v) >> 20], 1u);
    }
    __syncthreads();
    unsigned int* gb = g + b * 4096;
    for (int i = t; i < 4096; i += 256)
        if (h[i]) atomicAdd(&gb[i], h[i]);
}

// ---------------------------------------------------------------------------
// Parallel 3-round radix select (bits 12/12/8) for BOTH k=26214 (threshold)
// and k=80 (candidate cutoff), sharing the same histogram passes.
// ---------------------------------------------------------------------------

__global__ void k_hist2(const float* __restrict__ sal,
                        const unsigned int* __restrict__ prefA,
                        const unsigned int* __restrict__ prefB,
                        unsigned int* __restrict__ gA, unsigned int* __restrict__ gB) {
    __shared__ unsigned int hA[4096];
    __shared__ unsigned int hB[4096];
    int t = threadIdx.x;
    int b = blockIdx.x >> 5;
    int start = (blockIdx.x & 31) * 8192;
    const float* p = sal + (size_t)b * HW;
    unsigned int pA = prefA[b], pB = prefB[b];
    for (int i = t; i < 4096; i += 256) { hA[i] = 0u; hB[i] = 0u; }
    __syncthreads();
    for (int j = 0; j < 32; ++j) {
        unsigned int u = __float_as_uint(p[start + j * 256 + t]);
        unsigned int hi = u >> 20, mid = (u >> 8) & 4095u;
        if (hi == pA) atomicAdd(&hA[mid], 1u);
        if (hi == pB) atomicAdd(&hB[mid], 1u);
    }
    __syncthreads();
    unsigned int* ga = gA + b * 4096;
    unsigned int* gb2 = gB + b * 4096;
    for (int i = t; i < 4096; i += 256) {
        if (hA[i]) atomicAdd(&ga[i], hA[i]);
        if (hB[i]) atomicAdd(&gb2[i], hB[i]);
    }
}

__global__ void k_hist3(const float* __restrict__ sal,
                        const unsigned int* __restrict__ prefA,
                        const unsigned int* __restrict__ prefB,
                        unsigned int* __restrict__ gA, unsigned int* __restrict__ gB) {
    __shared__ unsigned int hA[256];
    __shared__ unsigned int hB[256];
    int t = threadIdx.x;
    int b = blockIdx.x >> 5;
    int start = (blockIdx.x & 31) * 8192;
    const float* p = sal + (size_t)b * HW;
    unsigned int pA = prefA[b], pB = prefB[b];
    hA[t] = 0u; hB[t] = 0u;
    __syncthreads();
    for (int j = 0; j < 32; ++j) {
        unsigned int u = __float_as_uint(p[start + j * 256 + t]);
        unsigned int hi = u >> 8, lo = u & 255u;
        if (hi == pA) atomicAdd(&hA[lo], 1u);
        if (hi == pB) atomicAdd(&hB[lo], 1u);
    }
    __syncthreads();
    unsigned int* ga = gA + b * 256;
    unsigned int* gb2 = gB + b * 256;
    if (hA[t]) atomicAdd(&ga[t], hA[t]);
    if (hB[t]) atomicAdd(&gb2[t], hB[t]);
}

// Find bin d (from top) s.t. suffix count crosses krem.
__device__ void radix_step(const unsigned int* __restrict__ h, int nbins, int krem,
                           int t, unsigned int* tsum, int* sbin, int* skrem) {
    int bpt = nbins >> 8;
    unsigned int s = 0;
    for (int j = 0; j < bpt; ++j) s += h[t * bpt + j];
    tsum[t] = s;
    __syncthreads();
    if (t == 0) {
        unsigned int cum = 0; int seg = 0;
        for (int d = 255; d >= 0; --d) {
            unsigned int c2 = cum + tsum[d];
            if ((int)c2 >= krem) { seg = d; break; }
            cum = c2;
        }
        unsigned int c = cum;
        for (int j = bpt - 1; j >= 0; --j) {
            unsigned int hv = h[seg * bpt + j];
            if ((int)(c + hv) >= krem) { *sbin = seg * bpt + j; *skrem = krem - (int)c; break; }
            c += hv;
        }
    }
    __syncthreads();
}

__global__ void k_scan1(const unsigned int* __restrict__ g,
                        unsigned int* prefA, int* kremA, unsigned int* prefB, int* kremB) {
    __shared__ unsigned int tsum[256];
    __shared__ int sbin, skrem;
    int b = blockIdx.x, t = threadIdx.x;
    radix_step(g + b * 4096, 4096, KSEL, t, tsum, &sbin, &skrem);
    if (t == 0) { prefA[b] = (unsigned int)sbin; kremA[b] = skrem; }
    __syncthreads();
    radix_step(g + b * 4096, 4096, MCAND, t, tsum, &sbin, &skrem);
    if (t == 0) { prefB[b] = (unsigned int)sbin; kremB[b] = skrem; }
}

__global__ void k_scan2(const unsigned int* __restrict__ gA, const unsigned int* __restrict__ gB,
                        unsigned int* prefA, int* kremA, unsigned int* prefB, int* kremB) {
    __shared__ unsigned int tsum[256];
    __shared__ int sbin, skrem;
    int b = blockIdx.x, t = threadIdx.x;
    radix_step(gA + b * 4096, 4096, kremA[b], t, tsum, &sbin, &skrem);
    if (t == 0) { prefA[b] = (prefA[b] << 12) | (unsigned int)sbin; kremA[b] = skrem; }
    __syncthreads();
    radix_step(gB + b * 4096, 4096, kremB[b], t, tsum, &sbin, &skrem);
    if (t == 0) { prefB[b] = (prefB[b] << 12) | (unsigned int)sbin; kremB[b] = skrem; }
}

__global__ void k_scan3(const unsigned int* __restrict__ gA, const unsigned int* __restrict__ gB,
                        const unsigned int* prefA, const int* kremA,
                        const unsigned int* prefB, const int* kremB,
                        unsigned int* __restrict__ ucut) {
    __shared__ unsigned int tsum[256];
    __shared__ int sbin, skrem;
    __shared__ unsigned int thrbits;
    int b = blockIdx.x, t = threadIdx.x;
    radix_step(gA + b * 256, 256, kremA[b], t, tsum, &sbin, &skrem);
    if (t == 0) {
        unsigned int kth = (prefA[b] << 8) | (unsigned int)sbin;
        float thr = fmaxf(__uint_as_float(kth), 0.1f);
        thrbits = __float_as_uint(thr);
    }
    __syncthreads();
    radix_step(gB + b * 256, 256, kremB[b], t, tsum, &sbin, &skrem);
    if (t == 0) {
        unsigned int c80 = (prefB[b] << 8) | (unsigned int)sbin;
        ucut[b] = (c80 > thrbits) ? c80 : thrbits;   // uint order == float order (>=0)
    }
}

__global__ void k_collect(const float* __restrict__ sal, const unsigned int* __restrict__ ucut,
                          float* __restrict__ candv, int* __restrict__ candi,
                          int* __restrict__ ccnt) {
    int t = threadIdx.x;
    int b = blockIdx.x >> 5;
    int start = (blockIdx.x & 31) * 8192;
    const float* p = sal + (size_t)b * HW;
    unsigned int cut = ucut[b];
    for (int j = 0; j < 32; ++j) {
        int i = start + j * 256 + t;
        unsigned int u = __float_as_uint(p[i]);
        if (u >= cut) {
            int pos = atomicAdd(&ccnt[b], 1);
            if (pos < CAP) { candv[b * CAP + pos] = p[i]; candi[b * CAP + pos] = i; }
        }
    }
}

// Rank (value desc, index asc — lax.top_k tie rule), bitmask greedy NMS.
// No runtime-indexed thread-local arrays anywhere (they'd go to scratch).
__global__ void k_final(const float* __restrict__ candv, const int* __restrict__ candi,
                        const int* __restrict__ ccnt, float* __restrict__ out) {
    __shared__ float cval[CAP];
    __shared__ int   cidx[CAP];
    __shared__ int   si[MCAND];
    __shared__ float sx[MCAND];
    __shared__ float sy[MCAND];
    __shared__ unsigned long long nearLo[MCAND];
    __shared__ unsigned long long nearHi[MCAND];
    int b = blockIdx.x, t = threadIdx.x;
    int n = min(ccnt[b], CAP);
    for (int i = t; i < n; i += 256) { cval[i] = candv[b * CAP + i]; cidx[i] = candi[b * CAP + i]; }
    __syncthreads();
    int m = min(n, MCAND);
    for (int i = t; i < n; i += 256) {
        float vi = cval[i]; int ii = cidx[i];
        int rank = 0;
        for (int j = 0; j < n; j++) {
            float vj = cval[j];
            if (vj > vi || (vj == vi && cidx[j] < ii)) rank++;
        }
        if (rank < MCAND) si[rank] = ii;
    }
    __syncthreads();
    for (int i = t; i < m; i += 256) {
        sx[i] = (float)(si[i] & 511);
        sy[i] = (float)(si[i] >> 9);
    }
    __syncthreads();
    for (int i = t; i < m; i += 256) {
        unsigned long long lo = 0ull, hi = 0ull;
        float x = sx[i], y = sy[i];
        for (int j = 0; j < m; j++) {
            float dx = sx[j] - x, dy = sy[j] - y;
            if (dx * dx + dy * dy < 100.0f) {
                if (j < 64) lo |= (1ull << j);
                else        hi |= (1ull << (j - 64));
            }
        }
        nearLo[i] = lo; nearHi[i] = hi;
    }
    __syncthreads();
    if (t == 0) {
        unsigned long long kLo = 0ull, kHi = 0ull;
        int cnt = 0;
        for (int i = 0; i < m; i++) {
            bool near_kept = ((nearLo[i] & kLo) | (nearHi[i] & kHi)) != 0ull;
            if (!near_kept) {
                out[b * 10 + 2 * cnt]     = sx[i];
                out[b * 10 + 2 * cnt + 1] = sy[i];
                out[160 + b * 5 + cnt]    = 1.0f;
                if (i < 64) kLo |= (1ull << i); else kHi |= (1ull << (i - 64));
                cnt++;
                if (cnt == TOPK) break;
            }
        }
        for (int j = cnt; j < TOPK; j++) {
            out[b * 10 + 2 * j]     = -1.0f;
            out[b * 10 + 2 * j + 1] = -1.0f;
            out[160 + b * 5 + j]    = -1.0f;
        }
    }
}

extern "C" void kernel_launch(void* const* d_in, const int* in_sizes, int n_in,
                              void* d_out, int out_size, void* d_ws, size_t ws_size,
                              hipStream_t stream) {
    const float* img = (const float*)d_in[0];
    float* out = (float*)d_out;
    char* ws = (char*)d_ws;

    // ws layout (bytes):
    //   [0, 32M)   : A (complex spectrum, in-place through k_colfft).
    //                Dead after k_mag_hblur. Then reused:
    //                  [0, ~1.1M) hists + ccnt + cand   (memset after vblur)
    //                  [20M, 20M+128K) pmn/pmx partials (written by vblur)
    //   [32M, 48M) : hb (h-blurred saliency)
    //   [48M, 64M) : salb (v-blurred)
    //   [64M, +448): scalar stats
    float2* A    = (float2*)ws;
    float*  hb   = (float*)(ws + 33554432UL);
    float*  salb = (float*)(ws + 50331648UL);

    unsigned int* hist1  = (unsigned int*)(ws + 0UL);        // 16*4096 u32 = 256KB
    unsigned int* hist2a = (unsigned int*)(ws + 262144UL);   // 256KB
    unsigned int* hist2b = (unsigned int*)(ws + 524288UL);   // 256KB
    unsigned int* hist3a = (unsigned int*)(ws + 786432UL);   // 16KB
    unsigned int* hist3b = (unsigned int*)(ws + 802816UL);   // 16KB
    int*          ccnt   = (int*)(ws + 819200UL);            // 64B
    const size_t  ZEROBYTES = 819264UL;
    float*        candv  = (float*)(ws + 851968UL);          // 128KB
    int*          candi  = (int*)(ws + 983040UL);            // 128KB

    float* pmn = (float*)(ws + 20971520UL);                  // 64KB (16384 f32)
    float* pmx = (float*)(ws + 21037056UL);                  // 64KB

    char* stats = ws + 67108864UL;
    unsigned int* prefA = (unsigned int*)(stats + 0);
    int*          kremA = (int*)(stats + 64);
    unsigned int* prefB = (unsigned int*)(stats + 128);
    int*          kremB = (int*)(stats + 192);
    unsigned int* ucut  = (unsigned int*)(stats + 256);
    float*        mnf   = (float*)(stats + 320);
    float*        mxf   = (float*)(stats + 384);

    float* salout = out + 240;   // sal region of d_out

    k_win_rowfft<<<dim3(8192), dim3(256), 0, stream>>>(img, A);     // DIF along W
    k_colfft<<<dim3(1024), dim3(256), 0, stream>>>(A);              // DIF-H + phase + DIT-H
    k_mag_hblur<<<dim3(8192), dim3(256), 0, stream>>>(A, hb);       // DIT-W + |.|^2 + hblur
    k_vblur<<<dim3(16384), dim3(256), 0, stream>>>(hb, salb, pmn, pmx);
    hipMemsetAsync(ws, 0, ZEROBYTES, stream);                       // hists + ccnt (A dead)
    k_reduce<<<dim3(BATCH), dim3(256), 0, stream>>>(pmn, pmx, mnf, mxf);
    k_norm_hist<<<dim3(512), dim3(256), 0, stream>>>(salb, mnf, mxf, salout, hist1);
    k_scan1<<<dim3(BATCH), dim3(256), 0, stream>>>(hist1, prefA, kremA, prefB, kremB);
    k_hist2<<<dim3(512), dim3(256), 0, stream>>>(salout, prefA, prefB, hist2a, hist2b);
    k_scan2<<<dim3(BATCH), dim3(256), 0, stream>>>(hist2a, hist2b, prefA, kremA, prefB, kremB);
    k_hist3<<<dim3(512), dim3(256), 0, stream>>>(salout, prefA, prefB, hist3a, hist3b);
    k_scan3<<<dim3(BATCH), dim3(256), 0, stream>>>(hist3a, hist3b, prefA, kremA, prefB, kremB, ucut);
    k_collect<<<dim3(512), dim3(256), 0, stream>>>(salout, ucut, candv, candi, ccnt);
    k_final<<<dim3(BATCH), dim3(256), 0, stream>>>(candv, candi, ccnt, out);
}

// Round 6
// 249.842 us; speedup vs baseline: 1.0463x; 1.0463x over previous
//
#include <hip/hip_runtime.h>
#include <math.h>

#define BATCH 16
#define HW 262144          // 512*512
#define KSEL 26214         // int(0.1 * 262144)
#define MCAND 80           // TOP_K * CAND_MULT
#define TOPK 5
#define CAP 2048

// ---------------------------------------------------------------------------
// In-place radix-2 FFT, N=512:
//   forward DIF: natural input -> bit-reversed output
//   inverse DIT: bit-reversed input -> natural output
// DIT(DIF(x)) = N*x elementwise; phase normalize is elementwise, axes are
// independent, so the bit-reversed intermediate order is unobservable.
// Twiddles via HW v_sin/v_cos (argument in revolutions, |rev| <= 0.5).
// ---------------------------------------------------------------------------

// Gaussian blur coefficients, sigma=1, 5-tap.
#define GW0 0.05448868454964294f
#define GW1 0.24420134200323332f
#define GW2 0.40261994689424746f

// K1: window + forward DIF FFT along W. One block per (b, h) row.
__global__ void k_win_rowfft(const float* __restrict__ img, float2* __restrict__ A) {
    __shared__ float re[512], im[512];
    int row = blockIdx.x;           // b*512 + h
    int h = row & 511;
    int t = threadIdx.x;
    float wr = 0.5f * (1.0f - __builtin_amdgcn_cosf((float)h * (1.0f / 511.0f)));
    const float* p = img + (size_t)row * 512;
    for (int i = t; i < 512; i += 256) {
        float wc = 0.5f * (1.0f - __builtin_amdgcn_cosf((float)i * (1.0f / 511.0f)));
        re[i] = p[i] * wr * wc;
        im[i] = 0.0f;
    }
    __syncthreads();
    #pragma unroll
    for (int hh = 256; hh >= 1; hh >>= 1) {
        int r = t & (hh - 1);
        int j = ((t & ~(hh - 1)) << 1) | r;
        float rev = -((float)r * (0.5f / (float)hh));
        float sn = __builtin_amdgcn_sinf(rev);
        float cs = __builtin_amdgcn_cosf(rev);
        float ax = re[j], ay = im[j];
        float bx = re[j + hh], by = im[j + hh];
        re[j] = ax + bx; im[j] = ay + by;
        float cx = ax - bx, cy = ay - by;
        re[j + hh] = cs * cx - sn * cy;
        im[j + hh] = cs * cy + sn * cx;
        __syncthreads();
    }
    float2* out = A + (size_t)row * 512;
    for (int i = t; i < 512; i += 256) out[i] = make_float2(re[i], im[i]);
}

// Fused H-axis pass on 512x16 column tiles (full 128B line per row-chunk):
// load -> fwd DIF along H -> phase-only normalize -> inv DIT along H -> store.
// 512 blocks = 16 images x 32 col-groups, 512 threads.
// LDS column stride 517 (== 5 words mod 32): all access patterns <= 2-way.
#define CSTR 517
__global__ __launch_bounds__(512) void k_colfft(float2* __restrict__ X) {
    __shared__ float re[16 * CSTR];
    __shared__ float im[16 * CSTR];
    int b = blockIdx.x >> 5;
    int c0 = (blockIdx.x & 31) * 16;
    int t = threadIdx.x;
    float2* base = X + (size_t)b * HW + c0;
    // load: float4 = 2 interleaved complex cols; 8 lanes cover 16 cols = 128B
    #pragma unroll
    for (int ii = 0; ii < 8; ++ii) {
        int linear = ii * 512 + t;        // 0..4095
        int cp = linear & 7;              // column pair
        int e  = linear >> 3;             // row
        const float4 v = *reinterpret_cast<const float4*>(&base[(size_t)e * 512 + cp * 2]);
        int a0 = (cp * 2) * CSTR + e;
        int a1 = a0 + CSTR;
        re[a0] = v.x; im[a0] = v.y;
        re[a1] = v.z; im[a1] = v.w;
    }
    __syncthreads();
    int c = t & 15, tt = t >> 4;          // 32 threads per column
    float* cr = re + c * CSTR;
    float* ci = im + c * CSTR;
    // forward DIF along H
    for (int hh = 256; hh >= 1; hh >>= 1) {
        #pragma unroll
        for (int kk = 0; kk < 8; ++kk) {
            int k = kk * 32 + tt;
            int r = k & (hh - 1);
            int j = ((k & ~(hh - 1)) << 1) | r;
            float rev = -((float)r * (0.5f / (float)hh));
            float sn = __builtin_amdgcn_sinf(rev);
            float cs = __builtin_amdgcn_cosf(rev);
            float ax = cr[j], ay = ci[j];
            float bx = cr[j + hh], by = ci[j + hh];
            cr[j] = ax + bx; ci[j] = ay + by;
            float cx = ax - bx, cy = ay - by;
            cr[j + hh] = cs * cx - sn * cy;
            ci[j + hh] = cs * cy + sn * cx;
        }
        __syncthreads();
    }
    // phase-only normalize (elementwise; order-agnostic)
    #pragma unroll
    for (int ii = 0; ii < 16; ++ii) {
        int linear = ii * 512 + t;        // 0..8191
        int cc = linear & 15, e = linear >> 4;
        int a = cc * CSTR + e;
        float x = re[a], y = im[a];
        float m2 = x * x + y * y;
        if (m2 > 0.0f) {
            float inv = rsqrtf(m2);
            re[a] = x * inv; im[a] = y * inv;
        } else {
            re[a] = 1.0f; im[a] = 0.0f;
        }
    }
    __syncthreads();
    // inverse DIT along H
    for (int hh = 1; hh <= 256; hh <<= 1) {
        #pragma unroll
        for (int kk = 0; kk < 8; ++kk) {
            int k = kk * 32 + tt;
            int r = k & (hh - 1);
            int j = ((k & ~(hh - 1)) << 1) | r;
            float rev = (float)r * (0.5f / (float)hh);
            float sn = __builtin_amdgcn_sinf(rev);
            float cs = __builtin_amdgcn_cosf(rev);
            float ax = cr[j], ay = ci[j];
            float bx0 = cr[j + hh], by0 = ci[j + hh];
            float bx = cs * bx0 - sn * by0;
            float by = cs * by0 + sn * bx0;
            cr[j] = ax + bx; ci[j] = ay + by;
            cr[j + hh] = ax - bx; ci[j + hh] = ay - by;
        }
        __syncthreads();
    }
    #pragma unroll
    for (int ii = 0; ii < 8; ++ii) {
        int linear = ii * 512 + t;
        int cp = linear & 7;
        int e  = linear >> 3;
        int a0 = (cp * 2) * CSTR + e;
        int a1 = a0 + CSTR;
        float4 v = make_float4(re[a0], im[a0], re[a1], im[a1]);
        *reinterpret_cast<float4*>(&base[(size_t)e * 512 + cp * 2]) = v;
    }
}

// Final inverse DIT FFT along W (bit-rev input) + 1/(H*W) scaling + |.|^2
// + horizontal 5-tap blur.
__global__ void k_mag_hblur(const float2* __restrict__ X, float* __restrict__ out) {
    __shared__ float re[512], im[512], smag[512];
    int row = blockIdx.x;
    int t = threadIdx.x;
    const float2* p = X + (size_t)row * 512;
    for (int i = t; i < 512; i += 256) {
        float2 v = p[i];
        re[i] = v.x; im[i] = v.y;
    }
    __syncthreads();
    #pragma unroll
    for (int hh = 1; hh <= 256; hh <<= 1) {
        int r = t & (hh - 1);
        int j = ((t & ~(hh - 1)) << 1) | r;
        float rev = (float)r * (0.5f / (float)hh);
        float sn = __builtin_amdgcn_sinf(rev);
        float cs = __builtin_amdgcn_cosf(rev);
        float ax = re[j], ay = im[j];
        float bx0 = re[j + hh], by0 = im[j + hh];
        float bx = cs * bx0 - sn * by0;
        float by = cs * by0 + sn * bx0;
        re[j] = ax + bx; im[j] = ay + by;
        re[j + hh] = ax - bx; im[j + hh] = ay - by;
        __syncthreads();
    }
    const float s = 3.814697265625e-06f;   // 1/262144, exact
    for (int i = t; i < 512; i += 256) {
        float rr = re[i] * s, ii = im[i] * s;
        smag[i] = rr * rr + ii * ii;
    }
    __syncthreads();
    float* o = out + (size_t)row * 512;
    for (int i = t; i < 512; i += 256) {
        float acc = GW2 * smag[i];
        if (i >= 1)   acc += GW1 * smag[i - 1];
        if (i >= 2)   acc += GW0 * smag[i - 2];
        if (i <= 510) acc += GW1 * smag[i + 1];
        if (i <= 509) acc += GW0 * smag[i + 2];
        o[i] = acc;
    }
}

// Vertical blur + per-BLOCK min/max partials (no atomics).
__global__ void k_vblur(const float* __restrict__ in, float* __restrict__ out,
                        float* __restrict__ pmn, float* __restrict__ pmx) {
    __shared__ float smn[256];
    __shared__ float smx[256];
    int t = threadIdx.x;
    int i = blockIdx.x * 256 + t;
    int y = (i >> 9) & 511;
    float acc = GW2 * in[i];
    if (y >= 1)   acc += GW1 * in[i - 512];
    if (y >= 2)   acc += GW0 * in[i - 1024];
    if (y <= 510) acc += GW1 * in[i + 512];
    if (y <= 509) acc += GW0 * in[i + 1024];
    out[i] = acc;
    smn[t] = acc; smx[t] = acc;
    __syncthreads();
    for (int s = 128; s > 0; s >>= 1) {
        if (t < s) { smn[t] = fminf(smn[t], smn[t + s]); smx[t] = fmaxf(smx[t], smx[t + s]); }
        __syncthreads();
    }
    if (t == 0) { pmn[blockIdx.x] = smn[0]; pmx[blockIdx.x] = smx[0]; }
}

// Fold 1024 partials per image -> mnf/mxf.
__global__ void k_reduce(const float* __restrict__ pmn, const float* __restrict__ pmx,
                         float* __restrict__ mnf, float* __restrict__ mxf) {
    __shared__ float smn[256];
    __shared__ float smx[256];
    int b = blockIdx.x, t = threadIdx.x;
    float lmn = INFINITY, lmx = -INFINITY;
    for (int j = t; j < 1024; j += 256) {
        lmn = fminf(lmn, pmn[b * 1024 + j]);
        lmx = fmaxf(lmx, pmx[b * 1024 + j]);
    }
    smn[t] = lmn; smx[t] = lmx;
    __syncthreads();
    for (int s = 128; s > 0; s >>= 1) {
        if (t < s) { smn[t] = fminf(smn[t], smn[t + s]); smx[t] = fmaxf(smx[t], smx[t + s]); }
        __syncthreads();
    }
    if (t == 0) { mnf[b] = smn[0]; mxf[b] = smx[0]; }
}

// Normalize + border mask -> final saliency (d_out), fused with hist round 1.
__global__ void k_norm_hist(const float* __restrict__ in, const float* __restrict__ mnf,
                            const float* __restrict__ mxf, float* __restrict__ out,
                            unsigned int* __restrict__ g) {
    __shared__ unsigned int h[4096];
    int t = threadIdx.x;
    int b = blockIdx.x >> 5;
    int base = b * HW + (blockIdx.x & 31) * 8192;
    float mn = mnf[b], mx = mxf[b];
    float inv = 1.0f / (mx - mn + 1e-8f);
    for (int i = t; i < 4096; i += 256) h[i] = 0u;
    __syncthreads();
    for (int j = 0; j < 32; ++j) {
        int idx = base + j * 256 + t;
        float v = (in[idx] - mn) * inv;
        int xx = idx & 511, yy = (idx >> 9) & 511;
        bool inside = (xx >= 12) && (xx < 500) && (yy >= 12) && (yy < 500);
        v = inside ? v : 0.0f;
        out[idx] = v;
        atomicAdd(&h[__float_as_uint(v) >> 20], 1u);
    }
    __syncthreads();
    unsigned int* gb = g + b * 4096;
    for (int i = t; i < 4096; i += 256)
        if (h[i]) atomicAdd(&gb[i], h[i]);
}

// ---------------------------------------------------------------------------
// Parallel 3-round radix select (bits 12/12/8) for BOTH k=26214 (threshold)
// and k=80 (candidate cutoff), sharing the same histogram passes.
// ---------------------------------------------------------------------------

__global__ void k_hist2(const float* __restrict__ sal,
                        const unsigned int* __restrict__ prefA,
                        const unsigned int* __restrict__ prefB,
                        unsigned int* __restrict__ gA, unsigned int* __restrict__ gB) {
    __shared__ unsigned int hA[4096];
    __shared__ unsigned int hB[4096];
    int t = threadIdx.x;
    int b = blockIdx.x >> 5;
    int start = (blockIdx.x & 31) * 8192;
    const float* p = sal + (size_t)b * HW;
    unsigned int pA = prefA[b], pB = prefB[b];
    for (int i = t; i < 4096; i += 256) { hA[i] = 0u; hB[i] = 0u; }
    __syncthreads();
    for (int j = 0; j < 32; ++j) {
        unsigned int u = __float_as_uint(p[start + j * 256 + t]);
        unsigned int hi = u >> 20, mid = (u >> 8) & 4095u;
        if (hi == pA) atomicAdd(&hA[mid], 1u);
        if (hi == pB) atomicAdd(&hB[mid], 1u);
    }
    __syncthreads();
    unsigned int* ga = gA + b * 4096;
    unsigned int* gb2 = gB + b * 4096;
    for (int i = t; i < 4096; i += 256) {
        if (hA[i]) atomicAdd(&ga[i], hA[i]);
        if (hB[i]) atomicAdd(&gb2[i], hB[i]);
    }
}

__global__ void k_hist3(const float* __restrict__ sal,
                        const unsigned int* __restrict__ prefA,
                        const unsigned int* __restrict__ prefB,
                        unsigned int* __restrict__ gA, unsigned int* __restrict__ gB) {
    __shared__ unsigned int hA[256];
    __shared__ unsigned int hB[256];
    int t = threadIdx.x;
    int b = blockIdx.x >> 5;
    int start = (blockIdx.x & 31) * 8192;
    const float* p = sal + (size_t)b * HW;
    unsigned int pA = prefA[b], pB = prefB[b];
    hA[t] = 0u; hB[t] = 0u;
    __syncthreads();
    for (int j = 0; j < 32; ++j) {
        unsigned int u = __float_as_uint(p[start + j * 256 + t]);
        unsigned int hi = u >> 8, lo = u & 255u;
        if (hi == pA) atomicAdd(&hA[lo], 1u);
        if (hi == pB) atomicAdd(&hB[lo], 1u);
    }
    __syncthreads();
    unsigned int* ga = gA + b * 256;
    unsigned int* gb2 = gB + b * 256;
    if (hA[t]) atomicAdd(&ga[t], hA[t]);
    if (hB[t]) atomicAdd(&gb2[t], hB[t]);
}

// Find bin d (from top) s.t. suffix count crosses krem.
__device__ void radix_step(const unsigned int* __restrict__ h, int nbins, int krem,
                           int t, unsigned int* tsum, int* sbin, int* skrem) {
    int bpt = nbins >> 8;
    unsigned int s = 0;
    for (int j = 0; j < bpt; ++j) s += h[t * bpt + j];
    tsum[t] = s;
    __syncthreads();
    if (t == 0) {
        unsigned int cum = 0; int seg = 0;
        for (int d = 255; d >= 0; --d) {
            unsigned int c2 = cum + tsum[d];
            if ((int)c2 >= krem) { seg = d; break; }
            cum = c2;
        }
        unsigned int c = cum;
        for (int j = bpt - 1; j >= 0; --j) {
            unsigned int hv = h[seg * bpt + j];
            if ((int)(c + hv) >= krem) { *sbin = seg * bpt + j; *skrem = krem - (int)c; break; }
            c += hv;
        }
    }
    __syncthreads();
}

__global__ void k_scan1(const unsigned int* __restrict__ g,
                        unsigned int* prefA, int* kremA, unsigned int* prefB, int* kremB) {
    __shared__ unsigned int tsum[256];
    __shared__ int sbin, skrem;
    int b = blockIdx.x, t = threadIdx.x;
    radix_step(g + b * 4096, 4096, KSEL, t, tsum, &sbin, &skrem);
    if (t == 0) { prefA[b] = (unsigned int)sbin; kremA[b] = skrem; }
    __syncthreads();
    radix_step(g + b * 4096, 4096, MCAND, t, tsum, &sbin, &skrem);
    if (t == 0) { prefB[b] = (unsigned int)sbin; kremB[b] = skrem; }
}

__global__ void k_scan2(const unsigned int* __restrict__ gA, const unsigned int* __restrict__ gB,
                        unsigned int* prefA, int* kremA, unsigned int* prefB, int* kremB) {
    __shared__ unsigned int tsum[256];
    __shared__ int sbin, skrem;
    int b = blockIdx.x, t = threadIdx.x;
    radix_step(gA + b * 4096, 4096, kremA[b], t, tsum, &sbin, &skrem);
    if (t == 0) { prefA[b] = (prefA[b] << 12) | (unsigned int)sbin; kremA[b] = skrem; }
    __syncthreads();
    radix_step(gB + b * 4096, 4096, kremB[b], t, tsum, &sbin, &skrem);
    if (t == 0) { prefB[b] = (prefB[b] << 12) | (unsigned int)sbin; kremB[b] = skrem; }
}

__global__ void k_scan3(const unsigned int* __restrict__ gA, const unsigned int* __restrict__ gB,
                        const unsigned int* prefA, const int* kremA,
                        const unsigned int* prefB, const int* kremB,
                        unsigned int* __restrict__ ucut) {
    __shared__ unsigned int tsum[256];
    __shared__ int sbin, skrem;
    __shared__ unsigned int thrbits;
    int b = blockIdx.x, t = threadIdx.x;
    radix_step(gA + b * 256, 256, kremA[b], t, tsum, &sbin, &skrem);
    if (t == 0) {
        unsigned int kth = (prefA[b] << 8) | (unsigned int)sbin;
        float thr = fmaxf(__uint_as_float(kth), 0.1f);
        thrbits = __float_as_uint(thr);
    }
    __syncthreads();
    radix_step(gB + b * 256, 256, kremB[b], t, tsum, &sbin, &skrem);
    if (t == 0) {
        unsigned int c80 = (prefB[b] << 8) | (unsigned int)sbin;
        ucut[b] = (c80 > thrbits) ? c80 : thrbits;   // uint order == float order (>=0)
    }
}

__global__ void k_collect(const float* __restrict__ sal, const unsigned int* __restrict__ ucut,
                          float* __restrict__ candv, int* __restrict__ candi,
                          int* __restrict__ ccnt) {
    int t = threadIdx.x;
    int b = blockIdx.x >> 5;
    int start = (blockIdx.x & 31) * 8192;
    const float* p = sal + (size_t)b * HW;
    unsigned int cut = ucut[b];
    for (int j = 0; j < 32; ++j) {
        int i = start + j * 256 + t;
        unsigned int u = __float_as_uint(p[i]);
        if (u >= cut) {
            int pos = atomicAdd(&ccnt[b], 1);
            if (pos < CAP) { candv[b * CAP + pos] = p[i]; candi[b * CAP + pos] = i; }
        }
    }
}

// Rank (value desc, index asc — lax.top_k tie rule), bitmask greedy NMS.
// No runtime-indexed thread-local arrays anywhere (they'd go to scratch).
__global__ void k_final(const float* __restrict__ candv, const int* __restrict__ candi,
                        const int* __restrict__ ccnt, float* __restrict__ out) {
    __shared__ float cval[CAP];
    __shared__ int   cidx[CAP];
    __shared__ int   si[MCAND];
    __shared__ float sx[MCAND];
    __shared__ float sy[MCAND];
    __shared__ unsigned long long nearLo[MCAND];
    __shared__ unsigned long long nearHi[MCAND];
    int b = blockIdx.x, t = threadIdx.x;
    int n = min(ccnt[b], CAP);
    for (int i = t; i < n; i += 256) { cval[i] = candv[b * CAP + i]; cidx[i] = candi[b * CAP + i]; }
    __syncthreads();
    int m = min(n, MCAND);
    for (int i = t; i < n; i += 256) {
        float vi = cval[i]; int ii = cidx[i];
        int rank = 0;
        for (int j = 0; j < n; j++) {
            float vj = cval[j];
            if (vj > vi || (vj == vi && cidx[j] < ii)) rank++;
        }
        if (rank < MCAND) si[rank] = ii;
    }
    __syncthreads();
    for (int i = t; i < m; i += 256) {
        sx[i] = (float)(si[i] & 511);
        sy[i] = (float)(si[i] >> 9);
    }
    __syncthreads();
    for (int i = t; i < m; i += 256) {
        unsigned long long lo = 0ull, hi = 0ull;
        float x = sx[i], y = sy[i];
        for (int j = 0; j < m; j++) {
            float dx = sx[j] - x, dy = sy[j] - y;
            if (dx * dx + dy * dy < 100.0f) {
                if (j < 64) lo |= (1ull << j);
                else        hi |= (1ull << (j - 64));
            }
        }
        nearLo[i] = lo; nearHi[i] = hi;
    }
    __syncthreads();
    if (t == 0) {
        unsigned long long kLo = 0ull, kHi = 0ull;
        int cnt = 0;
        for (int i = 0; i < m; i++) {
            bool near_kept = ((nearLo[i] & kLo) | (nearHi[i] & kHi)) != 0ull;
            if (!near_kept) {
                out[b * 10 + 2 * cnt]     = sx[i];
                out[b * 10 + 2 * cnt + 1] = sy[i];
                out[160 + b * 5 + cnt]    = 1.0f;
                if (i < 64) kLo |= (1ull << i); else kHi |= (1ull << (i - 64));
                cnt++;
                if (cnt == TOPK) break;
            }
        }
        for (int j = cnt; j < TOPK; j++) {
            out[b * 10 + 2 * j]     = -1.0f;
            out[b * 10 + 2 * j + 1] = -1.0f;
            out[160 + b * 5 + j]    = -1.0f;
        }
    }
}

extern "C" void kernel_launch(void* const* d_in, const int* in_sizes, int n_in,
                              void* d_out, int out_size, void* d_ws, size_t ws_size,
                              hipStream_t stream) {
    const float* img = (const float*)d_in[0];
    float* out = (float*)d_out;
    char* ws = (char*)d_ws;

    // ws layout (bytes):
    //   [0, 32M)   : A (complex spectrum, in-place through k_colfft).
    //                Dead after k_mag_hblur. Then reused:
    //                  [0, ~1.1M) hists + ccnt + cand   (memset after vblur)
    //                  [20M, 20M+128K) pmn/pmx partials (written by vblur)
    //   [32M, 48M) : hb (h-blurred saliency)
    //   [48M, 64M) : salb (v-blurred)
    //   [64M, +448): scalar stats
    float2* A    = (float2*)ws;
    float*  hb   = (float*)(ws + 33554432UL);
    float*  salb = (float*)(ws + 50331648UL);

    unsigned int* hist1  = (unsigned int*)(ws + 0UL);        // 16*4096 u32 = 256KB
    unsigned int* hist2a = (unsigned int*)(ws + 262144UL);   // 256KB
    unsigned int* hist2b = (unsigned int*)(ws + 524288UL);   // 256KB
    unsigned int* hist3a = (unsigned int*)(ws + 786432UL);   // 16KB
    unsigned int* hist3b = (unsigned int*)(ws + 802816UL);   // 16KB
    int*          ccnt   = (int*)(ws + 819200UL);            // 64B
    const size_t  ZEROBYTES = 819264UL;
    float*        candv  = (float*)(ws + 851968UL);          // 128KB
    int*          candi  = (int*)(ws + 983040UL);            // 128KB

    float* pmn = (float*)(ws + 20971520UL);                  // 64KB (16384 f32)
    float* pmx = (float*)(ws + 21037056UL);                  // 64KB

    char* stats = ws + 67108864UL;
    unsigned int* prefA = (unsigned int*)(stats + 0);
    int*          kremA = (int*)(stats + 64);
    unsigned int* prefB = (unsigned int*)(stats + 128);
    int*          kremB = (int*)(stats + 192);
    unsigned int* ucut  = (unsigned int*)(stats + 256);
    float*        mnf   = (float*)(stats + 320);
    float*        mxf   = (float*)(stats + 384);

    float* salout = out + 240;   // sal region of d_out

    k_win_rowfft<<<dim3(8192), dim3(256), 0, stream>>>(img, A);     // DIF along W
    k_colfft<<<dim3(512), dim3(512), 0, stream>>>(A);               // DIF-H + phase + DIT-H
    k_mag_hblur<<<dim3(8192), dim3(256), 0, stream>>>(A, hb);       // DIT-W + |.|^2 + hblur
    k_vblur<<<dim3(16384), dim3(256), 0, stream>>>(hb, salb, pmn, pmx);
    hipMemsetAsync(ws, 0, ZEROBYTES, stream);                       // hists + ccnt (A dead)
    k_reduce<<<dim3(BATCH), dim3(256), 0, stream>>>(pmn, pmx, mnf, mxf);
    k_norm_hist<<<dim3(512), dim3(256), 0, stream>>>(salb, mnf, mxf, salout, hist1);
    k_scan1<<<dim3(BATCH), dim3(256), 0, stream>>>(hist1, prefA, kremA, prefB, kremB);
    k_hist2<<<dim3(512), dim3(256), 0, stream>>>(salout, prefA, prefB, hist2a, hist2b);
    k_scan2<<<dim3(BATCH), dim3(256), 0, stream>>>(hist2a, hist2b, prefA, kremA, prefB, kremB);
    k_hist3<<<dim3(512), dim3(256), 0, stream>>>(salout, prefA, prefB, hist3a, hist3b);
    k_scan3<<<dim3(BATCH), dim3(256), 0, stream>>>(hist3a, hist3b, prefA, kremA, prefB, kremB, ucut);
    k_collect<<<dim3(512), dim3(256), 0, stream>>>(salout, ucut, candv, candi, ccnt);
    k_final<<<dim3(BATCH), dim3(256), 0, stream>>>(candv, candi, ccnt, out);
}